// Round 16
// baseline (124.075 us; speedup 1.0000x reference)
//
#include <hip/hip_runtime.h>
#include <hip/hip_bf16.h>
#include <math.h>

#define NS 16
#define H  48
#define TB 512            // edges per block-tile
#define THREADS 512       // 8 waves; wave-private 64-edge sub-tiles (m=4)

typedef __attribute__((ext_vector_type(8))) short bf16x8;
typedef __attribute__((ext_vector_type(4))) float f32x4;

// ---- LDS layout (halfword offsets) ----
// W1 frags f=0..2 @ f*768          (half0 512 + half1 256; bias via B1H)
// W2 frags u=0..19 @ 2304 + u*896  (half0 512 + half1 256 + k=48..55 bias 128)
// B1H bf16[48] @ 20224 ; ZO 8 zeros @ 20272
// ATO [512][64] bf16 @ 20280: A -> T -> msg f32[512][32]
//   (col 48 = 1.0 for bias-fold; cols 49..63 = 0)
// XO  [512][16] bf16 @ 53048
#define W2O   2304
#define B1H   20224
#define ZO    20272
#define ATO   20280
#define XO_   53048
#define SMEM_HW 61240    // 122480 B -> 1 block/CU, 8 waves
#define MSGF  10140      // float idx of ATO
#define WCPY  2535       // uint4 count of wpack image (40560 B)

__device__ __forceinline__ short f2bf(float f) {
    unsigned b = __float_as_uint(f);
    unsigned r = (b + 0x7FFFu + ((b >> 16) & 1u)) >> 16;
    return (short)r;
}
__device__ __forceinline__ float bf2f(short s) {
    return __uint_as_float(((unsigned)(unsigned short)s) << 16);
}
// HW packed f32->bf16 (RNE), 2 elements per instruction
__device__ __forceinline__ unsigned cvtpk(float lo, float hi) {
    unsigned r;
    asm("v_cvt_pk_bf16_f32 %0, %1, %2" : "=v"(r) : "v"(lo), "v"(hi));
    return r;
}
__device__ __forceinline__ uint4 pk8(float4 a, float4 b) {
    uint4 q;
    q.x = cvtpk(a.x, a.y); q.y = cvtpk(a.z, a.w);
    q.z = cvtpk(b.x, b.y); q.w = cvtpk(b.z, b.w);
    return q;
}

// ---------- prep (blocks 0-5) + hist (blocks 6+) ----------
__global__ __launch_bounds__(256) void prep_hist_kernel(
    const float* __restrict__ fc1_w, const float* __restrict__ fc2_w,
    const float* __restrict__ fc1_b, const float* __restrict__ fc2_b,
    short* __restrict__ wpack,
    const int* __restrict__ edge_index, int* __restrict__ deg, int E)
{
    if (blockIdx.x < 6) {
        int t = blockIdx.x * 256 + threadIdx.x;
        if (t < 1472) {                 // 23 frags x 64 lanes
            int f = t >> 6, l = t & 63;
            bool isW1 = (f < 3);
            int u = isW1 ? f : (f - 3);
            int n = u * 16 + (l & 15);
            const float* W = isW1 ? fc1_w : fc2_w;
            int ldw = isW1 ? 48 : 320;
            int base = isW1 ? (f * 768) : (W2O + u * 896);
            short* d0 = wpack + base + l * 8;
            #pragma unroll
            for (int i = 0; i < 8; ++i)
                d0[i] = f2bf(W[((l >> 4) * 8 + i) * ldw + n]);
            if (l < 32) {               // half1: k = 32..47
                short* d1 = wpack + base + 512 + l * 8;
                #pragma unroll
                for (int i = 0; i < 8; ++i)
                    d1[i] = f2bf(W[(32 + (l >> 4) * 8 + i) * ldw + n]);
            } else if (!isW1 && l < 48) {   // W2 bias block: k = 48..55
                short* d1 = wpack + base + 512 + l * 8;
                d1[0] = f2bf(fc2_b[n]);
                #pragma unroll
                for (int i = 1; i < 8; ++i) d1[i] = 0;
            }
        } else if (t < 1520) {
            wpack[B1H + (t - 1472)] = f2bf(fc1_b[t - 1472]);
        } else if (t < 1528) {
            wpack[ZO + (t - 1520)] = 0;
        }
    } else {
        int i = (blockIdx.x - 6) * 256 + threadIdx.x;
        if (i < E) atomicAdd(deg + edge_index[i], 1);
    }
}

// ---------- main edge kernel: 512 edges/block, 8 waves, m=4 ----------
__global__ __launch_bounds__(THREADS, 1) void edge_mfma_kernel(
    const float* __restrict__ node_attr,
    const float* __restrict__ edge_attr,
    const float* __restrict__ edge_vec,
    const short* __restrict__ wpack,
    const int*   __restrict__ edge_index,
    float* __restrict__ msg,       // [E][32] CSR-ordered messages
    int*   __restrict__ cursor,
    int E)
{
    __shared__ __align__(16) short smemS[SMEM_HW];
    float* smemF = (float*)smemS;
    const int tid = threadIdx.x;
    const int base = blockIdx.x * TB;
    const int l  = tid & 63;
    const int wv = tid >> 6;     // 0..7
    const int g  = l >> 4;
    const int c  = l & 15;
    const int rb = wv * 64;      // 64 rows per wave

    // hoisted latency-critical index loads (1 thread per edge-row)
    const int r = tid;           // wave wv stages rows [rb, rb+64) == its lanes
    const int e = base + r;
    const int ce = e < E ? e : (E - 1);
    const int sI_raw = edge_index[ce];
    const int dI = edge_index[E + ce];

    // per-row metadata in registers (lane rloc holds row rb+rloc's values)
    float shx_r = 0.f, shy_r = 0.f, shz_r = 0.f;
    int slot_r = 0;

    // ---- W image staging: one linear coalesced copy (5 iters) ----
    for (int idx = tid; idx < WCPY; idx += THREADS) {
        uint4 v = ((const uint4*)wpack)[idx];
        *(uint4*)&smemS[idx * 8] = v;
    }

    // ---- per-edge staging: 1 thread/edge, wave-private rows ----
    {
        const float* ap = edge_attr + (size_t)ce * H;
        float4 A0 = *(const float4*)(ap + 0);
        float4 A1 = *(const float4*)(ap + 4);
        float4 A2 = *(const float4*)(ap + 8);
        float4 A3 = *(const float4*)(ap + 12);
        float4 A4 = *(const float4*)(ap + 16);
        float4 A5 = *(const float4*)(ap + 20);
        float4 A6 = *(const float4*)(ap + 24);
        float4 A7 = *(const float4*)(ap + 28);
        float4 A8 = *(const float4*)(ap + 32);
        float4 A9 = *(const float4*)(ap + 36);
        float4 Aa = *(const float4*)(ap + 40);
        float4 Ab = *(const float4*)(ap + 44);
        const float* xp = node_attr + (size_t)dI * NS;
        float4 X0 = *(const float4*)(xp + 0);
        float4 X1 = *(const float4*)(xp + 4);
        float4 X2 = *(const float4*)(xp + 8);
        float4 X3 = *(const float4*)(xp + 12);
        if (e >= E) {
            A0 = make_float4(0,0,0,0); A1 = A0; A2 = A0; A3 = A0; A4 = A0; A5 = A0;
            A6 = A0; A7 = A0; A8 = A0; A9 = A0; Aa = A0; Ab = A0;
            X0 = A0; X1 = A0; X2 = A0; X3 = A0;
        }
        const int s8 = (r & 7) << 3;
        *(uint4*)&smemS[ATO + r * 64 + ((0 << 3) ^ s8)] = pk8(A0, A1);
        *(uint4*)&smemS[ATO + r * 64 + ((1 << 3) ^ s8)] = pk8(A2, A3);
        *(uint4*)&smemS[ATO + r * 64 + ((2 << 3) ^ s8)] = pk8(A4, A5);
        *(uint4*)&smemS[ATO + r * 64 + ((3 << 3) ^ s8)] = pk8(A6, A7);
        *(uint4*)&smemS[ATO + r * 64 + ((4 << 3) ^ s8)] = pk8(A8, A9);
        *(uint4*)&smemS[ATO + r * 64 + ((5 << 3) ^ s8)] = pk8(Aa, Ab);
        {   // K-pad chunks 6,7: col48 = 1.0 (bias multiplier), rest 0
            uint4 zq; zq.x = 0x00003F80u; zq.y = 0u; zq.z = 0u; zq.w = 0u;
            uint4 zz; zz.x = 0u; zz.y = 0u; zz.z = 0u; zz.w = 0u;
            *(uint4*)&smemS[ATO + r * 64 + ((6 << 3) ^ s8)] = zq;
            *(uint4*)&smemS[ATO + r * 64 + ((7 << 3) ^ s8)] = zz;
        }
        *(uint4*)&smemS[XO_ + r * 16 + 0] = pk8(X0, X1);
        *(uint4*)&smemS[XO_ + r * 16 + 8] = pk8(X2, X3);
        // spherical harmonics l=1
        float vx = 0.f, vy = 0.f, vz = 0.f;
        if (e < E) {
            vx = edge_vec[3 * (size_t)ce + 0];
            vy = edge_vec[3 * (size_t)ce + 1];
            vz = edge_vec[3 * (size_t)ce + 2];
        }
        float rn = 1.0f / (sqrtf(vx*vx + vy*vy + vz*vz) + 1e-8f);
        const float c1 = 1.7320508075688772f;
        shx_r = c1 * vx * rn; shy_r = c1 * vy * rn; shz_r = c1 * vz * rn;
        if (e < E) slot_r = atomicAdd(cursor + sI_raw, 1);
    }
    __syncthreads();   // W is cross-wave; the rest is wave-private

    // ---- GEMM1: T = relu(A @ W1 + b1), 4 row-fragments per wave ----
    bf16x8 a0[4], a1[4];
    #pragma unroll
    for (int m = 0; m < 4; ++m) {
        int row = rb + m * 16 + c, s8 = (row & 7) << 3;
        a0[m] = *(const bf16x8*)&smemS[ATO + row * 64 + ((g * 8) ^ s8)];
        a1[m] = *(const bf16x8*)&smemS[ATO + row * 64 + ((32 + g * 8) ^ s8)];
    }
    #pragma unroll
    for (int fr = 0; fr < 3; ++fr) {
        bf16x8 b0 = *(const bf16x8*)&smemS[fr * 768 + l * 8];
        bf16x8 b1 = *(const bf16x8*)&smemS[(l < 32) ? (fr * 768 + 512 + l * 8) : ZO];
        float bia = bf2f(smemS[B1H + fr * 16 + c]);
        #pragma unroll
        for (int m = 0; m < 4; ++m) {
            f32x4 acc = {0.f, 0.f, 0.f, 0.f};
            acc = __builtin_amdgcn_mfma_f32_16x16x32_bf16(a0[m], b0, acc, 0, 0, 0);
            acc = __builtin_amdgcn_mfma_f32_16x16x32_bf16(a1[m], b1, acc, 0, 0, 0);
            float t0 = fmaxf(acc[0] + bia, 0.f);
            float t1 = fmaxf(acc[1] + bia, 0.f);
            float t2 = fmaxf(acc[2] + bia, 0.f);
            float t3 = fmaxf(acc[3] + bia, 0.f);
            unsigned p01 = cvtpk(t0, t1);
            unsigned p23 = cvtpk(t2, t3);
            int row0 = rb + m * 16 + g * 4;
            int col = fr * 16 + c;
            smemS[ATO + (row0+0) * 64 + (col ^ (((row0+0) & 7) << 3))] = (short)p01;
            smemS[ATO + (row0+1) * 64 + (col ^ (((row0+1) & 7) << 3))] = (short)(p01 >> 16);
            smemS[ATO + (row0+2) * 64 + (col ^ (((row0+2) & 7) << 3))] = (short)p23;
            smemS[ATO + (row0+3) * 64 + (col ^ (((row0+3) & 7) << 3))] = (short)(p23 >> 16);
        }
    }

    // ---- fragments for GEMM2 (T col48 = 1.0 folds the fc2 bias) ----
    bf16x8 tf0[4], tf1[4];
    #pragma unroll
    for (int m = 0; m < 4; ++m) {
        int row = rb + m * 16 + c, s8 = (row & 7) << 3;
        tf0[m] = *(const bf16x8*)&smemS[ATO + row * 64 + ((g * 8) ^ s8)];
        tf1[m] = *(const bf16x8*)&smemS[ATO + row * 64 + ((32 + g * 8) ^ s8)];
    }
    bf16x8 xr0[4][4], xr1[4][4];
    #pragma unroll
    for (int m = 0; m < 4; ++m)
        #pragma unroll
        for (int j = 0; j < 4; ++j) {
            int row = rb + m * 16 + g * 4 + j;
            xr0[m][j] = *(const bf16x8*)&smemS[XO_ + row * 16];
            xr1[m][j] = *(const bf16x8*)&smemS[XO_ + row * 16 + 8];
        }

    // ---- GEMM2 + fused contraction (bias already inside acc) ----
    float o0[4][4] = {{0,0,0,0},{0,0,0,0},{0,0,0,0},{0,0,0,0}};
    float o1[4][4] = {{0,0,0,0},{0,0,0,0},{0,0,0,0},{0,0,0,0}};
    const int s2 = c >> 2;
    #pragma unroll
    for (int u = 0; u < 20; ++u) {
        const int wb = W2O + u * 896;
        bf16x8 b0 = *(const bf16x8*)&smemS[wb + l * 8];
        bf16x8 b1 = *(const bf16x8*)&smemS[(l < 48) ? (wb + 512 + l * 8) : ZO];
        #pragma unroll
        for (int m = 0; m < 4; ++m) {
            f32x4 acc = {0.f, 0.f, 0.f, 0.f};
            acc = __builtin_amdgcn_mfma_f32_16x16x32_bf16(tf0[m], b0, acc, 0, 0, 0);
            acc = __builtin_amdgcn_mfma_f32_16x16x32_bf16(tf1[m], b1, acc, 0, 0, 0);
            if (u < 16) {
                #pragma unroll
                for (int j = 0; j < 4; ++j) {
                    float xu = bf2f(u < 8 ? xr0[m][j][u] : xr1[m][j][u - 8]);
                    o0[m][j] = fmaf(xu, acc[j], o0[m][j]);
                }
            } else {
                const int f = u - 16;
                #pragma unroll
                for (int j = 0; j < 4; ++j) {
                    float e0, e1, e2, e3;
                    if (f < 2) {
                        e0 = bf2f(xr0[m][j][f*4+0]); e1 = bf2f(xr0[m][j][f*4+1]);
                        e2 = bf2f(xr0[m][j][f*4+2]); e3 = bf2f(xr0[m][j][f*4+3]);
                    } else {
                        e0 = bf2f(xr1[m][j][(f-2)*4+0]); e1 = bf2f(xr1[m][j][(f-2)*4+1]);
                        e2 = bf2f(xr1[m][j][(f-2)*4+2]); e3 = bf2f(xr1[m][j][(f-2)*4+3]);
                    }
                    float xu = e0;
                    xu = (s2 == 1) ? e1 : xu;
                    xu = (s2 == 2) ? e2 : xu;
                    xu = (s2 == 3) ? e3 : xu;
                    o1[m][j] = fmaf(xu, acc[j], o1[m][j]);
                }
            }
        }
    }
    #pragma unroll
    for (int m = 0; m < 4; ++m)
        #pragma unroll
        for (int j = 0; j < 4; ++j) {
            o1[m][j] += __shfl_xor(o1[m][j], 4);
            o1[m][j] += __shfl_xor(o1[m][j], 8);
        }

    // ---- epilogue: transpose messages through LDS (ATO rows now dead) ----
    const float inv = 0.25f;
    #pragma unroll
    for (int m = 0; m < 4; ++m)
        #pragma unroll
        for (int j = 0; j < 4; ++j) {
            const int rloc = m*16 + g*4 + j;       // 0..63 == staging lane
            const int rr = rb + rloc;
            float shx = __shfl(shx_r, rloc);
            float shy = __shfl(shy_r, rloc);
            float shz = __shfl(shz_r, rloc);
            int lsrc = (g << 4) + (c < 12 ? c / 3 : 0);
            float ov = __shfl(o1[m][j], lsrc);
            int m3 = c - 3 * (c / 3);
            float shm = (m3 == 0) ? shx : ((m3 == 1) ? shy : shz);
            float v2 = (c < 12) ? ov * shm * inv : 0.f;
            smemF[MSGF + rr * 32 + c]      = o0[m][j] * inv;
            smemF[MSGF + rr * 32 + 16 + c] = v2;
        }

    // ---- full-line stores: 8 lanes x float4 = one fully-dirty 128B line/edge ----
    #pragma unroll
    for (int it = 0; it < 8; ++it) {
        int rloc2 = it * 8 + (l >> 3);             // 0..63 == staging lane
        int r2 = rb + rloc2;
        int ch = (l & 7) * 4;
        int e2 = base + r2;
        int slot = __shfl(slot_r, rloc2);
        float4 val = *(const float4*)&smemF[MSGF + r2 * 32 + ch];
        if (e2 < E) *(float4*)(msg + (size_t)slot * 32 + ch) = val;
    }
}

// Unordered CSR offsets: block-local scan + one atomic base per block.
__global__ __launch_bounds__(1024) void offsets_kernel(
    const int* __restrict__ deg, int* __restrict__ starts,
    int* __restrict__ cursor, int* __restrict__ gtotal, int N)
{
    __shared__ int lds[1024];
    __shared__ int base_s;
    const int t = threadIdx.x;
    const int i = blockIdx.x * 1024 + t;
    int v = (i < N) ? deg[i] : 0;
    lds[t] = v;
    __syncthreads();
    int acc = v;
    for (int off = 1; off < 1024; off <<= 1) {
        int u = (t >= off) ? lds[t - off] : 0;
        __syncthreads();
        acc += u;
        lds[t] = acc;
        __syncthreads();
    }
    if (t == 1023) base_s = atomicAdd(gtotal, acc);
    __syncthreads();
    int excl = acc - v;
    if (i < N) {
        int s = base_s + excl;
        starts[i] = s;
        cursor[i] = s;
    }
}

// one half-wave per node; 4-way unrolled independent loads
__global__ __launch_bounds__(256) void sum_kernel(
    const float* __restrict__ msg, const int* __restrict__ starts,
    const int* __restrict__ deg, float* __restrict__ out, int N)
{
    int n = (blockIdx.x * blockDim.x + threadIdx.x) >> 5;
    int ch = threadIdx.x & 31;
    if (n >= N) return;
    int s = starts[n], d = deg[n];
    const float* mb = msg + (size_t)s * 32 + ch;
    float a0 = 0.f, a1 = 0.f, a2 = 0.f, a3 = 0.f;
    int k = 0;
    for (; k + 4 <= d; k += 4) {
        a0 += mb[(size_t)(k + 0) * 32];
        a1 += mb[(size_t)(k + 1) * 32];
        a2 += mb[(size_t)(k + 2) * 32];
        a3 += mb[(size_t)(k + 3) * 32];
    }
    if (k + 2 <= d) {
        a0 += mb[(size_t)(k + 0) * 32];
        a1 += mb[(size_t)(k + 1) * 32];
        k += 2;
    }
    if (k < d) a2 += mb[(size_t)k * 32];
    float acc = (a0 + a1) + (a2 + a3);
    if (ch < 28) out[(size_t)n * 28 + ch] = acc / fmaxf((float)d, 1.0f);
}

__global__ __launch_bounds__(256) void finalize_kernel(
    float* __restrict__ out, const float* __restrict__ cnt, int total)
{
    int i = blockIdx.x * blockDim.x + threadIdx.x;
    if (i < total) {
        float cv = cnt[i / 28];
        out[i] = out[i] / fmaxf(cv, 1.0f);
    }
}

// compact fp32 fallback (only if workspace is unexpectedly small)
__global__ __launch_bounds__(256) void naive_kernel(
    const float* __restrict__ node_attr, const float* __restrict__ edge_attr,
    const float* __restrict__ edge_vec, const float* __restrict__ fc1_w,
    const float* __restrict__ fc1_b, const float* __restrict__ fc2_w,
    const float* __restrict__ fc2_b, const int* __restrict__ edge_index,
    float* __restrict__ out, float* __restrict__ cnt, int E)
{
    int e = blockIdx.x * blockDim.x + threadIdx.x;
    if (e >= E) return;
    float a[H];
    for (int i = 0; i < H; ++i) a[i] = edge_attr[(size_t)e*H + i];
    int dst = edge_index[E + e];
    float x[NS];
    for (int i = 0; i < NS; ++i) x[i] = node_attr[(size_t)dst*NS + i];
    float o0[NS] = {0}, o1v[4] = {0};
    for (int k = 0; k < H; ++k) {
        float tk = fc1_b[k];
        for (int j = 0; j < H; ++j) tk = fmaf(a[j], fc1_w[j*H + k], tk);
        tk = fmaxf(tk, 0.f);
        const float* row = fc2_w + k*320;
        for (int u = 0; u < NS; ++u) {
            float q = tk * x[u];
            for (int w = 0; w < NS; ++w) o0[w] = fmaf(q, row[u*NS+w], o0[w]);
            for (int v = 0; v < 4; ++v) o1v[v] = fmaf(q, row[256+u*4+v], o1v[v]);
        }
    }
    for (int u = 0; u < NS; ++u) {
        float xu = x[u];
        for (int w = 0; w < NS; ++w) o0[w] = fmaf(xu, fc2_b[u*NS+w], o0[w]);
        for (int v = 0; v < 4; ++v) o1v[v] = fmaf(xu, fc2_b[256+u*4+v], o1v[v]);
    }
    float vx = edge_vec[3*(size_t)e], vy = edge_vec[3*(size_t)e+1], vz = edge_vec[3*(size_t)e+2];
    float rn = 1.0f / (sqrtf(vx*vx+vy*vy+vz*vz) + 1e-8f);
    const float c1 = 1.7320508075688772f;
    float sx = c1*vx*rn, sy = c1*vy*rn, sz = c1*vz*rn;
    int src = edge_index[e];
    float* ob = out + (size_t)src * 28;
    for (int w = 0; w < NS; ++w) atomicAdd(ob + w, o0[w] * 0.25f);
    for (int v = 0; v < 4; ++v) {
        float q = o1v[v] * 0.25f;
        atomicAdd(ob + 16 + 3*v + 0, q * sx);
        atomicAdd(ob + 16 + 3*v + 1, q * sy);
        atomicAdd(ob + 16 + 3*v + 2, q * sz);
    }
    atomicAdd(cnt + src, 1.0f);
}

extern "C" void kernel_launch(void* const* d_in, const int* in_sizes, int n_in,
                              void* d_out, int out_size, void* d_ws, size_t ws_size,
                              hipStream_t stream) {
    const float* node_attr  = (const float*)d_in[0];
    const float* edge_attr  = (const float*)d_in[1];
    const float* edge_vec   = (const float*)d_in[2];
    const float* fc1_w      = (const float*)d_in[3];
    const float* fc1_b      = (const float*)d_in[4];
    const float* fc2_w      = (const float*)d_in[5];
    const float* fc2_b      = (const float*)d_in[6];
    const int*   edge_index = (const int*)d_in[7];

    int E = in_sizes[2] / 3;      // 400000
    int N = in_sizes[0] / NS;     // 50000
    float* out = (float*)d_out;

    size_t msg_b  = (size_t)E * 32 * sizeof(float);
    size_t ints_b = (3 * (size_t)N + 1) * sizeof(int);
    size_t wpk_b  = (size_t)WCPY * 16;   // 40560 B
    size_t need   = msg_b + ints_b + wpk_b;

    if (ws_size >= need) {
        float* msg  = (float*)d_ws;
        int* ip     = (int*)((char*)d_ws + msg_b);
        int* deg    = ip;                 // [N]
        int* gtotal = ip + N;             // [1]
        int* starts = ip + N + 1;         // [N]
        int* cursor = ip + 2 * N + 1;     // [N]
        short* wpack = (short*)((char*)d_ws + msg_b + ints_b);

        hipMemsetAsync(deg, 0, ((size_t)N + 1) * sizeof(int), stream);
        int nhist = (E + 255) / 256;
        prep_hist_kernel<<<6 + nhist, 256, 0, stream>>>(
            fc1_w, fc2_w, fc1_b, fc2_b, wpack, edge_index, deg, E);
        offsets_kernel<<<(N + 1023) / 1024, 1024, 0, stream>>>(
            deg, starts, cursor, gtotal, N);
        edge_mfma_kernel<<<(E + TB - 1) / TB, THREADS, 0, stream>>>(
            node_attr, edge_attr, edge_vec, wpack, edge_index, msg, cursor, E);
        sum_kernel<<<((size_t)N * 32 + 255) / 256, 256, 0, stream>>>(
            msg, starts, deg, out, N);
    } else {
        float* cnt = (float*)d_ws;
        hipMemsetAsync(d_out, 0, (size_t)out_size * sizeof(float), stream);
        hipMemsetAsync(d_ws, 0, (size_t)N * sizeof(float), stream);
        naive_kernel<<<(E + 255) / 256, 256, 0, stream>>>(
            node_attr, edge_attr, edge_vec, fc1_w, fc1_b, fc2_w, fc2_b,
            edge_index, out, cnt, E);
        int total = N * 28;
        finalize_kernel<<<(total + 255) / 256, 256, 0, stream>>>(out, cnt, total);
    }
}

// Round 17
// 100.961 us; speedup vs baseline: 1.2289x; 1.2289x over previous
//
#include <hip/hip_runtime.h>
#include <hip/hip_bf16.h>
#include <math.h>

#define NS 16
#define H  48
#define TB 256            // edges per block-tile
#define THREADS 512       // 8 waves; wave-private 32-edge sub-tiles

typedef __attribute__((ext_vector_type(8))) short bf16x8;
typedef __attribute__((ext_vector_type(4))) float f32x4;

// ---- LDS layout (halfword offsets) ----
// W1 frags f=0..2 @ f*768          (half0 512 + half1 256; bias via B1H)
// W2 frags u=0..19 @ 2304 + u*896  (half0 512 + half1 256 + k=48..55 bias 128)
// B1H bf16[48] @ 20224 ; ZO 8 zeros @ 20272
// ATO [256][64] bf16 @ 20280: A -> T -> msg f32[256][32]
//   (col 48 = 1.0 for bias-fold; cols 49..63 = 0)
// XO  [256][16] bf16 @ 36664
#define W2O   2304
#define B1H   20224
#define ZO    20272
#define ATO   20280
#define XO_   36664
#define SMEM_HW 40760    // 81520 B -> best-known config (r13/r14)
#define MSGF  10140      // float idx of ATO
#define WCPY  2535       // uint4 count of wpack image (40560 B)

__device__ __forceinline__ short f2bf(float f) {
    unsigned b = __float_as_uint(f);
    unsigned r = (b + 0x7FFFu + ((b >> 16) & 1u)) >> 16;
    return (short)r;
}
__device__ __forceinline__ float bf2f(short s) {
    return __uint_as_float(((unsigned)(unsigned short)s) << 16);
}
// HW packed f32->bf16 (RNE), 2 elements per instruction
__device__ __forceinline__ unsigned cvtpk(float lo, float hi) {
    unsigned r;
    asm("v_cvt_pk_bf16_f32 %0, %1, %2" : "=v"(r) : "v"(lo), "v"(hi));
    return r;
}
__device__ __forceinline__ uint4 pk8(float4 a, float4 b) {
    uint4 q;
    q.x = cvtpk(a.x, a.y); q.y = cvtpk(a.z, a.w);
    q.z = cvtpk(b.x, b.y); q.w = cvtpk(b.z, b.w);
    return q;
}

// ---------- prep (blocks 0-5) + hist (blocks 6+) ----------
__global__ __launch_bounds__(256) void prep_hist_kernel(
    const float* __restrict__ fc1_w, const float* __restrict__ fc2_w,
    const float* __restrict__ fc1_b, const float* __restrict__ fc2_b,
    short* __restrict__ wpack,
    const int* __restrict__ edge_index, int* __restrict__ deg, int E)
{
    if (blockIdx.x < 6) {
        int t = blockIdx.x * 256 + threadIdx.x;
        if (t < 1472) {                 // 23 frags x 64 lanes
            int f = t >> 6, l = t & 63;
            bool isW1 = (f < 3);
            int u = isW1 ? f : (f - 3);
            int n = u * 16 + (l & 15);
            const float* W = isW1 ? fc1_w : fc2_w;
            int ldw = isW1 ? 48 : 320;
            int base = isW1 ? (f * 768) : (W2O + u * 896);
            short* d0 = wpack + base + l * 8;
            #pragma unroll
            for (int i = 0; i < 8; ++i)
                d0[i] = f2bf(W[((l >> 4) * 8 + i) * ldw + n]);
            if (l < 32) {               // half1: k = 32..47
                short* d1 = wpack + base + 512 + l * 8;
                #pragma unroll
                for (int i = 0; i < 8; ++i)
                    d1[i] = f2bf(W[(32 + (l >> 4) * 8 + i) * ldw + n]);
            } else if (!isW1 && l < 48) {   // W2 bias block: k = 48..55
                short* d1 = wpack + base + 512 + l * 8;
                d1[0] = f2bf(fc2_b[n]);
                #pragma unroll
                for (int i = 1; i < 8; ++i) d1[i] = 0;
            }
        } else if (t < 1520) {
            wpack[B1H + (t - 1472)] = f2bf(fc1_b[t - 1472]);
        } else if (t < 1528) {
            wpack[ZO + (t - 1520)] = 0;
        }
    } else {
        int i = (blockIdx.x - 6) * 256 + threadIdx.x;
        if (i < E) atomicAdd(deg + edge_index[i], 1);
    }
}

// ---------- main edge kernel (r14 best-known, bf16 msg stores) ----------
__global__ __launch_bounds__(THREADS, 2) void edge_mfma_kernel(
    const float* __restrict__ node_attr,
    const float* __restrict__ edge_attr,
    const float* __restrict__ edge_vec,
    const short* __restrict__ wpack,
    const int*   __restrict__ edge_index,
    unsigned short* __restrict__ msg,   // [E][32] bf16 CSR-ordered messages
    int*   __restrict__ cursor,
    int E)
{
    __shared__ __align__(16) short smemS[SMEM_HW];
    float* smemF = (float*)smemS;
    const int tid = threadIdx.x;
    const int base = blockIdx.x * TB;
    const int l  = tid & 63;
    const int wv = tid >> 6;     // 0..7
    const int g  = l >> 4;
    const int c  = l & 15;
    const int rb = wv * 32;

    // hoisted latency-critical index loads
    const int r = tid >> 1, h = tid & 1;   // wave wv stages rows [rb, rb+32)
    const int e = base + r;
    const int ce = e < E ? e : (E - 1);
    const int sI_raw = edge_index[ce];
    const int dI = edge_index[E + ce];

    // per-row metadata kept in registers (shfl'd in epilogue; rows are wave-owned)
    float shx_r = 0.f, shy_r = 0.f, shz_r = 0.f;
    int slot_r = 0;

    // ---- W image staging: one linear coalesced copy ----
    for (int idx = tid; idx < WCPY; idx += THREADS) {
        uint4 v = ((const uint4*)wpack)[idx];
        *(uint4*)&smemS[idx * 8] = v;
    }

    // ---- per-edge staging: 2 threads/edge, wave-private rows ----
    {
        const float* ap = edge_attr + (size_t)ce * H + h * 24;
        float4 A0 = *(const float4*)(ap + 0);
        float4 A1 = *(const float4*)(ap + 4);
        float4 A2 = *(const float4*)(ap + 8);
        float4 A3 = *(const float4*)(ap + 12);
        float4 A4 = *(const float4*)(ap + 16);
        float4 A5 = *(const float4*)(ap + 20);
        const float* xp = node_attr + (size_t)dI * NS + h * 8;
        float4 X0 = *(const float4*)(xp + 0);
        float4 X1 = *(const float4*)(xp + 4);
        if (e >= E) {
            A0 = make_float4(0,0,0,0); A1 = A0; A2 = A0; A3 = A0; A4 = A0; A5 = A0;
            X0 = A0; X1 = A0;
        }
        const int s8 = (r & 7) << 3;
        *(uint4*)&smemS[ATO + r * 64 + (((h*3 + 0) << 3) ^ s8)] = pk8(A0, A1);
        *(uint4*)&smemS[ATO + r * 64 + (((h*3 + 1) << 3) ^ s8)] = pk8(A2, A3);
        *(uint4*)&smemS[ATO + r * 64 + (((h*3 + 2) << 3) ^ s8)] = pk8(A4, A5);
        {   // K-pad chunk (6+h): h==0 writes col48 = 1.0 (bias multiplier), rest 0
            int az = ATO + r * 64 + (((6 + h) << 3) ^ s8);
            uint4 zq;
            zq.x = (h == 0) ? 0x00003F80u : 0u;
            zq.y = 0u; zq.z = 0u; zq.w = 0u;
            *(uint4*)&smemS[az] = zq;
        }
        *(uint4*)&smemS[XO_ + r * 16 + h * 8] = pk8(X0, X1);
        if (h == 0) {
            int sI = (e < E) ? sI_raw : 0;
            float vx = 0.f, vy = 0.f, vz = 0.f;
            if (e < E) {
                vx = edge_vec[3 * (size_t)ce + 0];
                vy = edge_vec[3 * (size_t)ce + 1];
                vz = edge_vec[3 * (size_t)ce + 2];
            }
            float rn = 1.0f / (sqrtf(vx*vx + vy*vy + vz*vz) + 1e-8f);
            const float c1 = 1.7320508075688772f;
            shx_r = c1 * vx * rn; shy_r = c1 * vy * rn; shz_r = c1 * vz * rn;
            if (e < E) slot_r = atomicAdd(cursor + sI, 1);
        }
    }
    __syncthreads();   // W is cross-wave; the rest is wave-private

    // ---- GEMM1: T = relu(A @ W1 + b1) ----
    bf16x8 a0[2], a1[2];
    #pragma unroll
    for (int m = 0; m < 2; ++m) {
        int row = rb + m * 16 + c, s8 = (row & 7) << 3;
        a0[m] = *(const bf16x8*)&smemS[ATO + row * 64 + ((g * 8) ^ s8)];
        a1[m] = *(const bf16x8*)&smemS[ATO + row * 64 + ((32 + g * 8) ^ s8)];
    }
    #pragma unroll
    for (int fr = 0; fr < 3; ++fr) {
        bf16x8 b0 = *(const bf16x8*)&smemS[fr * 768 + l * 8];
        bf16x8 b1 = *(const bf16x8*)&smemS[(l < 32) ? (fr * 768 + 512 + l * 8) : ZO];
        float bia = bf2f(smemS[B1H + fr * 16 + c]);
        #pragma unroll
        for (int m = 0; m < 2; ++m) {
            f32x4 acc = {0.f, 0.f, 0.f, 0.f};
            acc = __builtin_amdgcn_mfma_f32_16x16x32_bf16(a0[m], b0, acc, 0, 0, 0);
            acc = __builtin_amdgcn_mfma_f32_16x16x32_bf16(a1[m], b1, acc, 0, 0, 0);
            float t0 = fmaxf(acc[0] + bia, 0.f);
            float t1 = fmaxf(acc[1] + bia, 0.f);
            float t2 = fmaxf(acc[2] + bia, 0.f);
            float t3 = fmaxf(acc[3] + bia, 0.f);
            unsigned p01 = cvtpk(t0, t1);
            unsigned p23 = cvtpk(t2, t3);
            int row0 = rb + m * 16 + g * 4;
            int col = fr * 16 + c;
            smemS[ATO + (row0+0) * 64 + (col ^ (((row0+0) & 7) << 3))] = (short)p01;
            smemS[ATO + (row0+1) * 64 + (col ^ (((row0+1) & 7) << 3))] = (short)(p01 >> 16);
            smemS[ATO + (row0+2) * 64 + (col ^ (((row0+2) & 7) << 3))] = (short)p23;
            smemS[ATO + (row0+3) * 64 + (col ^ (((row0+3) & 7) << 3))] = (short)(p23 >> 16);
        }
    }

    // ---- fragments for GEMM2 (T col48 = 1.0 folds the fc2 bias) ----
    bf16x8 tf0[2], tf1[2];
    #pragma unroll
    for (int m = 0; m < 2; ++m) {
        int row = rb + m * 16 + c, s8 = (row & 7) << 3;
        tf0[m] = *(const bf16x8*)&smemS[ATO + row * 64 + ((g * 8) ^ s8)];
        tf1[m] = *(const bf16x8*)&smemS[ATO + row * 64 + ((32 + g * 8) ^ s8)];
    }
    bf16x8 xr0[2][4], xr1[2][4];
    #pragma unroll
    for (int m = 0; m < 2; ++m)
        #pragma unroll
        for (int j = 0; j < 4; ++j) {
            int row = rb + m * 16 + g * 4 + j;
            xr0[m][j] = *(const bf16x8*)&smemS[XO_ + row * 16];
            xr1[m][j] = *(const bf16x8*)&smemS[XO_ + row * 16 + 8];
        }

    // ---- GEMM2 + fused contraction (bias already inside acc) ----
    float o0[2][4] = {{0.f,0.f,0.f,0.f},{0.f,0.f,0.f,0.f}};
    float o1[2][4] = {{0.f,0.f,0.f,0.f},{0.f,0.f,0.f,0.f}};
    const int s2 = c >> 2;
    #pragma unroll
    for (int u = 0; u < 20; ++u) {
        const int wb = W2O + u * 896;
        bf16x8 b0 = *(const bf16x8*)&smemS[wb + l * 8];
        bf16x8 b1 = *(const bf16x8*)&smemS[(l < 48) ? (wb + 512 + l * 8) : ZO];
        #pragma unroll
        for (int m = 0; m < 2; ++m) {
            f32x4 acc = {0.f, 0.f, 0.f, 0.f};
            acc = __builtin_amdgcn_mfma_f32_16x16x32_bf16(tf0[m], b0, acc, 0, 0, 0);
            acc = __builtin_amdgcn_mfma_f32_16x16x32_bf16(tf1[m], b1, acc, 0, 0, 0);
            if (u < 16) {
                #pragma unroll
                for (int j = 0; j < 4; ++j) {
                    float xu = bf2f(u < 8 ? xr0[m][j][u] : xr1[m][j][u - 8]);
                    o0[m][j] = fmaf(xu, acc[j], o0[m][j]);
                }
            } else {
                const int f = u - 16;
                #pragma unroll
                for (int j = 0; j < 4; ++j) {
                    float e0, e1, e2, e3;
                    if (f < 2) {
                        e0 = bf2f(xr0[m][j][f*4+0]); e1 = bf2f(xr0[m][j][f*4+1]);
                        e2 = bf2f(xr0[m][j][f*4+2]); e3 = bf2f(xr0[m][j][f*4+3]);
                    } else {
                        e0 = bf2f(xr1[m][j][(f-2)*4+0]); e1 = bf2f(xr1[m][j][(f-2)*4+1]);
                        e2 = bf2f(xr1[m][j][(f-2)*4+2]); e3 = bf2f(xr1[m][j][(f-2)*4+3]);
                    }
                    float xu = e0;
                    xu = (s2 == 1) ? e1 : xu;
                    xu = (s2 == 2) ? e2 : xu;
                    xu = (s2 == 3) ? e3 : xu;
                    o1[m][j] = fmaf(xu, acc[j], o1[m][j]);
                }
            }
        }
    }
    #pragma unroll
    for (int m = 0; m < 2; ++m)
        #pragma unroll
        for (int j = 0; j < 4; ++j) {
            o1[m][j] += __shfl_xor(o1[m][j], 4);
            o1[m][j] += __shfl_xor(o1[m][j], 8);
        }

    // ---- epilogue: transpose messages through LDS (ATO rows now dead) ----
    const float inv = 0.25f;
    #pragma unroll
    for (int m = 0; m < 2; ++m)
        #pragma unroll
        for (int j = 0; j < 4; ++j) {
            const int rloc = m*16 + g*4 + j;
            const int rr = rb + rloc;
            const int srcl = rloc * 2;          // staging lane (h==0) for this row
            float shx = __shfl(shx_r, srcl);
            float shy = __shfl(shy_r, srcl);
            float shz = __shfl(shz_r, srcl);
            int lsrc = (g << 4) + (c < 12 ? c / 3 : 0);
            float ov = __shfl(o1[m][j], lsrc);
            int m3 = c - 3 * (c / 3);
            float shm = (m3 == 0) ? shx : ((m3 == 1) ? shy : shz);
            float v2 = (c < 12) ? ov * shm * inv : 0.f;
            smemF[MSGF + rr * 32 + c]      = o0[m][j] * inv;
            smemF[MSGF + rr * 32 + 16 + c] = v2;
        }

    // ---- bf16 stores: 8 lanes x uint2 = one fully-dirty 64B sector/edge ----
    #pragma unroll
    for (int it = 0; it < 4; ++it) {
        int rloc2 = it * 8 + (l >> 3);
        int r2 = rb + rloc2;
        int ch = (l & 7) * 4;
        int e2 = base + r2;
        int slot = __shfl(slot_r, rloc2 * 2);
        float4 val = *(const float4*)&smemF[MSGF + r2 * 32 + ch];
        if (e2 < E) {
            uint2 pv;
            pv.x = cvtpk(val.x, val.y);
            pv.y = cvtpk(val.z, val.w);
            *(uint2*)(msg + (size_t)slot * 32 + ch) = pv;
        }
    }
}

// Unordered CSR offsets: block-local scan + one atomic base per block.
__global__ __launch_bounds__(1024) void offsets_kernel(
    const int* __restrict__ deg, int* __restrict__ starts,
    int* __restrict__ cursor, int* __restrict__ gtotal, int N)
{
    __shared__ int lds[1024];
    __shared__ int base_s;
    const int t = threadIdx.x;
    const int i = blockIdx.x * 1024 + t;
    int v = (i < N) ? deg[i] : 0;
    lds[t] = v;
    __syncthreads();
    int acc = v;
    for (int off = 1; off < 1024; off <<= 1) {
        int u = (t >= off) ? lds[t - off] : 0;
        __syncthreads();
        acc += u;
        lds[t] = acc;
        __syncthreads();
    }
    if (t == 1023) base_s = atomicAdd(gtotal, acc);
    __syncthreads();
    int excl = acc - v;
    if (i < N) {
        int s = base_s + excl;
        starts[i] = s;
        cursor[i] = s;
    }
}

// one half-wave per node; 4-way unrolled independent bf16 loads
__global__ __launch_bounds__(256) void sum_kernel(
    const unsigned short* __restrict__ msg, const int* __restrict__ starts,
    const int* __restrict__ deg, float* __restrict__ out, int N)
{
    int n = (blockIdx.x * blockDim.x + threadIdx.x) >> 5;
    int ch = threadIdx.x & 31;
    if (n >= N) return;
    int s = starts[n], d = deg[n];
    const unsigned short* mb = msg + (size_t)s * 32 + ch;
    float a0 = 0.f, a1 = 0.f, a2 = 0.f, a3 = 0.f;
    int k = 0;
    for (; k + 4 <= d; k += 4) {
        a0 += bf2f((short)mb[(size_t)(k + 0) * 32]);
        a1 += bf2f((short)mb[(size_t)(k + 1) * 32]);
        a2 += bf2f((short)mb[(size_t)(k + 2) * 32]);
        a3 += bf2f((short)mb[(size_t)(k + 3) * 32]);
    }
    if (k + 2 <= d) {
        a0 += bf2f((short)mb[(size_t)(k + 0) * 32]);
        a1 += bf2f((short)mb[(size_t)(k + 1) * 32]);
        k += 2;
    }
    if (k < d) a2 += bf2f((short)mb[(size_t)k * 32]);
    float acc = (a0 + a1) + (a2 + a3);
    if (ch < 28) out[(size_t)n * 28 + ch] = acc / fmaxf((float)d, 1.0f);
}

__global__ __launch_bounds__(256) void finalize_kernel(
    float* __restrict__ out, const float* __restrict__ cnt, int total)
{
    int i = blockIdx.x * blockDim.x + threadIdx.x;
    if (i < total) {
        float cv = cnt[i / 28];
        out[i] = out[i] / fmaxf(cv, 1.0f);
    }
}

// compact fp32 fallback (only if workspace is unexpectedly small)
__global__ __launch_bounds__(256) void naive_kernel(
    const float* __restrict__ node_attr, const float* __restrict__ edge_attr,
    const float* __restrict__ edge_vec, const float* __restrict__ fc1_w,
    const float* __restrict__ fc1_b, const float* __restrict__ fc2_w,
    const float* __restrict__ fc2_b, const int* __restrict__ edge_index,
    float* __restrict__ out, float* __restrict__ cnt, int E)
{
    int e = blockIdx.x * blockDim.x + threadIdx.x;
    if (e >= E) return;
    float a[H];
    for (int i = 0; i < H; ++i) a[i] = edge_attr[(size_t)e*H + i];
    int dst = edge_index[E + e];
    float x[NS];
    for (int i = 0; i < NS; ++i) x[i] = node_attr[(size_t)dst*NS + i];
    float o0[NS] = {0}, o1v[4] = {0};
    for (int k = 0; k < H; ++k) {
        float tk = fc1_b[k];
        for (int j = 0; j < H; ++j) tk = fmaf(a[j], fc1_w[j*H + k], tk);
        tk = fmaxf(tk, 0.f);
        const float* row = fc2_w + k*320;
        for (int u = 0; u < NS; ++u) {
            float q = tk * x[u];
            for (int w = 0; w < NS; ++w) o0[w] = fmaf(q, row[u*NS+w], o0[w]);
            for (int v = 0; v < 4; ++v) o1v[v] = fmaf(q, row[256+u*4+v], o1v[v]);
        }
    }
    for (int u = 0; u < NS; ++u) {
        float xu = x[u];
        for (int w = 0; w < NS; ++w) o0[w] = fmaf(xu, fc2_b[u*NS+w], o0[w]);
        for (int v = 0; v < 4; ++v) o1v[v] = fmaf(xu, fc2_b[256+u*4+v], o1v[v]);
    }
    float vx = edge_vec[3*(size_t)e], vy = edge_vec[3*(size_t)e+1], vz = edge_vec[3*(size_t)e+2];
    float rn = 1.0f / (sqrtf(vx*vx+vy*vy+vz*vz) + 1e-8f);
    const float c1 = 1.7320508075688772f;
    float sx = c1*vx*rn, sy = c1*vy*rn, sz = c1*vz*rn;
    int src = edge_index[e];
    float* ob = out + (size_t)src * 28;
    for (int w = 0; w < NS; ++w) atomicAdd(ob + w, o0[w] * 0.25f);
    for (int v = 0; v < 4; ++v) {
        float q = o1v[v] * 0.25f;
        atomicAdd(ob + 16 + 3*v + 0, q * sx);
        atomicAdd(ob + 16 + 3*v + 1, q * sy);
        atomicAdd(ob + 16 + 3*v + 2, q * sz);
    }
    atomicAdd(cnt + src, 1.0f);
}

extern "C" void kernel_launch(void* const* d_in, const int* in_sizes, int n_in,
                              void* d_out, int out_size, void* d_ws, size_t ws_size,
                              hipStream_t stream) {
    const float* node_attr  = (const float*)d_in[0];
    const float* edge_attr  = (const float*)d_in[1];
    const float* edge_vec   = (const float*)d_in[2];
    const float* fc1_w      = (const float*)d_in[3];
    const float* fc1_b      = (const float*)d_in[4];
    const float* fc2_w      = (const float*)d_in[5];
    const float* fc2_b      = (const float*)d_in[6];
    const int*   edge_index = (const int*)d_in[7];

    int E = in_sizes[2] / 3;      // 400000
    int N = in_sizes[0] / NS;     // 50000
    float* out = (float*)d_out;

    size_t msg_b  = (size_t)E * 32 * sizeof(unsigned short);   // bf16 messages
    size_t ints_b = (3 * (size_t)N + 1) * sizeof(int);
    size_t wpk_b  = (size_t)WCPY * 16;   // 40560 B
    size_t need   = msg_b + ints_b + wpk_b;

    if (ws_size >= need) {
        unsigned short* msg = (unsigned short*)d_ws;
        int* ip     = (int*)((char*)d_ws + msg_b);
        int* deg    = ip;                 // [N]
        int* gtotal = ip + N;             // [1]
        int* starts = ip + N + 1;         // [N]
        int* cursor = ip + 2 * N + 1;     // [N]
        short* wpack = (short*)((char*)d_ws + msg_b + ints_b);

        hipMemsetAsync(deg, 0, ((size_t)N + 1) * sizeof(int), stream);
        int nhist = (E + 255) / 256;
        prep_hist_kernel<<<6 + nhist, 256, 0, stream>>>(
            fc1_w, fc2_w, fc1_b, fc2_b, wpack, edge_index, deg, E);
        offsets_kernel<<<(N + 1023) / 1024, 1024, 0, stream>>>(
            deg, starts, cursor, gtotal, N);
        edge_mfma_kernel<<<(E + TB - 1) / TB, THREADS, 0, stream>>>(
            node_attr, edge_attr, edge_vec, wpack, edge_index, msg, cursor, E);
        sum_kernel<<<((size_t)N * 32 + 255) / 256, 256, 0, stream>>>(
            msg, starts, deg, out, N);
    } else {
        float* cnt = (float*)d_ws;
        hipMemsetAsync(d_out, 0, (size_t)out_size * sizeof(float), stream);
        hipMemsetAsync(d_ws, 0, (size_t)N * sizeof(float), stream);
        naive_kernel<<<(E + 255) / 256, 256, 0, stream>>>(
            node_attr, edge_attr, edge_vec, fc1_w, fc1_b, fc2_w, fc2_b,
            edge_index, out, cnt, E);
        int total = N * 28;
        finalize_kernel<<<(total + 255) / 256, 256, 0, stream>>>(out, cnt, total);
    }
}